// Round 1
// baseline (137.051 us; speedup 1.0000x reference)
//
#include <hip/hip_runtime.h>
#include <hip/hip_bf16.h>

#define N_ROWS 8192
#define D_DIM  512

typedef __attribute__((ext_vector_type(8))) short short8;
typedef __attribute__((ext_vector_type(4))) float f32x4;

typedef const __attribute__((address_space(1))) void* gptr_t;
typedef __attribute__((address_space(3))) void* lptr_t;

static __device__ __forceinline__ void gload16(const void* g, void* l) {
    __builtin_amdgcn_global_load_lds((gptr_t)g, (lptr_t)l, 16, 0, 0);
}

// round-to-nearest-even f32 -> bf16 bits
static __device__ __forceinline__ unsigned short f2bf(float x) {
    unsigned u = __float_as_uint(x);
    unsigned r = (u + 0x7FFFu + ((u >> 16) & 1u)) >> 16;
    return (unsigned short)r;
}

// One wave per row: L2-normalize a row, write bf16, store 1/norm.
__global__ void norm_kernel(const float* __restrict__ cxr, const float* __restrict__ ehr,
                            unsigned short* __restrict__ cxr_b, unsigned short* __restrict__ ehr_b,
                            float* __restrict__ inva, float* __restrict__ invb) {
    const int row = blockIdx.x * 4 + (threadIdx.x >> 6);
    const int lane = threadIdx.x & 63;
    const float* src;
    unsigned short* dst;
    float* invp;
    int r;
    if (row < N_ROWS) {
        r = row; src = cxr + (size_t)r * D_DIM; dst = cxr_b + (size_t)r * D_DIM; invp = inva;
    } else {
        r = row - N_ROWS; src = ehr + (size_t)r * D_DIM; dst = ehr_b + (size_t)r * D_DIM; invp = invb;
    }
    const float4* s4 = (const float4*)(src + lane * 8);
    float4 a = s4[0], b = s4[1];
    float ss = a.x*a.x + a.y*a.y + a.z*a.z + a.w*a.w
             + b.x*b.x + b.y*b.y + b.z*b.z + b.w*b.w;
#pragma unroll
    for (int s = 1; s < 64; s <<= 1) ss += __shfl_xor(ss, s);
    // 1 / max(sqrt(ss), 1e-8) == rsqrt(max(ss, 1e-16))
    float inv = 1.0f / sqrtf(fmaxf(ss, 1e-16f));
    if (lane == 0) invp[r] = inv;
    float va[8] = {a.x, a.y, a.z, a.w, b.x, b.y, b.z, b.w};
    short8 o;
#pragma unroll
    for (int j = 0; j < 8; ++j) o[j] = (short)f2bf(va[j] * inv);
    *(short8*)(dst + lane * 8) = o;
}

// One wave per row: diag_i = dot(cxr_i, ehr_i) * inva_i * invb_i / temp   (full fp32)
__global__ void diag_kernel(const float* __restrict__ cxr, const float* __restrict__ ehr,
                            const float* __restrict__ inva, const float* __restrict__ invb,
                            const float* __restrict__ temp, float* __restrict__ dg) {
    const int row = blockIdx.x * 4 + (threadIdx.x >> 6);
    const int lane = threadIdx.x & 63;
    const float4* a4 = (const float4*)(cxr + (size_t)row * D_DIM + lane * 8);
    const float4* b4 = (const float4*)(ehr + (size_t)row * D_DIM + lane * 8);
    float4 a0 = a4[0], a1 = a4[1];
    float4 b0 = b4[0], b1 = b4[1];
    float d = a0.x*b0.x + a0.y*b0.y + a0.z*b0.z + a0.w*b0.w
            + a1.x*b1.x + a1.y*b1.y + a1.z*b1.z + a1.w*b1.w;
#pragma unroll
    for (int s = 1; s < 64; s <<= 1) d += __shfl_xor(d, s);
    if (lane == 0) dg[row] = d * inva[row] * invb[row] / temp[0];
}

// Fused: 128x128 bf16 MFMA tile of cos_sim, epilogue exp((cos-1)/temp),
// partial row/col sums -> global atomics. Diagonal elements excluded.
__global__ __launch_bounds__(256) void gemm_lse_kernel(
        const unsigned short* __restrict__ A, const unsigned short* __restrict__ B,
        const float* __restrict__ temp,
        float* __restrict__ row_sum, float* __restrict__ col_sum) {
    __shared__ short As[128 * 32];
    __shared__ short Bs[128 * 32];
    __shared__ float rs_l[128];
    __shared__ float cs_l[128];

    const int tid = threadIdx.x;
    const int lane = tid & 63;
    const int wid = tid >> 6;
    const int bm = blockIdx.x, bn = blockIdx.y;
    const int wr = wid >> 1, wc = wid & 1;

    if (tid < 128) { rs_l[tid] = 0.f; cs_l[tid] = 0.f; }

    // staging geometry: chunk c covers rows [c*16, c*16+16) of the [128][32] tile
    const int c0 = wid * 2, c1 = c0 + 1;
    const int r0 = c0 * 16 + (lane >> 2), col0 = (lane & 3) * 8;
    const int r1 = c1 * 16 + (lane >> 2), col1 = (lane & 3) * 8;
    const size_t aOff0 = (size_t)(bm * 128 + r0) * D_DIM + col0;
    const size_t aOff1 = (size_t)(bm * 128 + r1) * D_DIM + col1;
    const size_t bOff0 = (size_t)(bn * 128 + r0) * D_DIM + col0;
    const size_t bOff1 = (size_t)(bn * 128 + r1) * D_DIM + col1;
    short* AsD0 = As + c0 * 512;  // wave-uniform LDS bases
    short* AsD1 = As + c1 * 512;
    short* BsD0 = Bs + c0 * 512;
    short* BsD1 = Bs + c1 * 512;

    f32x4 acc[4][4] = {};

    const int lrow = lane & 15;
    const int lko = (lane >> 4) * 8;

    for (int kk = 0; kk < 16; ++kk) {
        const int ko = kk * 32;
        gload16(A + aOff0 + ko, AsD0);
        gload16(A + aOff1 + ko, AsD1);
        gload16(B + bOff0 + ko, BsD0);
        gload16(B + bOff1 + ko, BsD1);
        __syncthreads();
        short8 af[4], bf[4];
#pragma unroll
        for (int mi = 0; mi < 4; ++mi)
            af[mi] = *(const short8*)&As[(wr * 64 + mi * 16 + lrow) * 32 + lko];
#pragma unroll
        for (int ni = 0; ni < 4; ++ni)
            bf[ni] = *(const short8*)&Bs[(wc * 64 + ni * 16 + lrow) * 32 + lko];
#pragma unroll
        for (int mi = 0; mi < 4; ++mi)
#pragma unroll
            for (int ni = 0; ni < 4; ++ni)
                acc[mi][ni] = __builtin_amdgcn_mfma_f32_16x16x32_bf16(af[mi], bf[ni], acc[mi][ni], 0, 0, 0);
        __syncthreads();
    }

    const float invT = 1.0f / temp[0];
    const bool diagBlk = (bm == bn);

    float rowpart[16];
#pragma unroll
    for (int i = 0; i < 16; ++i) rowpart[i] = 0.f;
    float colpart[4] = {0.f, 0.f, 0.f, 0.f};

#pragma unroll
    for (int mi = 0; mi < 4; ++mi) {
#pragma unroll
        for (int ni = 0; ni < 4; ++ni) {
            f32x4 a = acc[mi][ni];
#pragma unroll
            for (int r = 0; r < 4; ++r) {
                float e = __expf((a[r] - 1.0f) * invT);
                if (diagBlk) {
                    int grow = wr * 64 + mi * 16 + (lane >> 4) * 4 + r;
                    int gcol = wc * 64 + ni * 16 + (lane & 15);
                    if (grow == gcol) e = 0.f;
                }
                rowpart[mi * 4 + r] += e;
                colpart[ni] += e;
            }
        }
    }

    // column sums: reduce across the 4 row-groups (lanes ^16, ^32)
#pragma unroll
    for (int ni = 0; ni < 4; ++ni) {
        float v = colpart[ni];
        v += __shfl_xor(v, 16);
        v += __shfl_xor(v, 32);
        if (lane < 16) atomicAdd(&cs_l[wc * 64 + ni * 16 + lane], v);
    }
    // row sums: reduce across the 16 columns held by the lane's group
#pragma unroll
    for (int idx = 0; idx < 16; ++idx) {
        float v = rowpart[idx];
        v += __shfl_xor(v, 1);
        v += __shfl_xor(v, 2);
        v += __shfl_xor(v, 4);
        v += __shfl_xor(v, 8);
        if ((lane & 15) == 0) {
            int mi = idx >> 2, r = idx & 3;
            atomicAdd(&rs_l[wr * 64 + mi * 16 + (lane >> 4) * 4 + r], v);
        }
    }
    __syncthreads();
    if (tid < 128) atomicAdd(&row_sum[bm * 128 + tid], rs_l[tid]);
    else           atomicAdd(&col_sum[bn * 128 + (tid - 128)], cs_l[tid - 128]);
}

// loss = mean_i [ 2M + log(rs_i) + log(cs_i) - 2*diag_i ],  M = 1/temp
__global__ void finalize_kernel(const float* __restrict__ rs, const float* __restrict__ cs,
                                const float* __restrict__ dg, const float* __restrict__ temp,
                                float* __restrict__ out) {
    const float M = 1.0f / temp[0];
    float acc = 0.f;
    for (int i = threadIdx.x; i < N_ROWS; i += 256)
        acc += 2.f * M + __logf(rs[i]) + __logf(cs[i]) - 2.f * dg[i];
#pragma unroll
    for (int s = 1; s < 64; s <<= 1) acc += __shfl_xor(acc, s);
    __shared__ float wsum[4];
    if ((threadIdx.x & 63) == 0) wsum[threadIdx.x >> 6] = acc;
    __syncthreads();
    if (threadIdx.x == 0)
        out[0] = (wsum[0] + wsum[1] + wsum[2] + wsum[3]) / (float)N_ROWS;
}

extern "C" void kernel_launch(void* const* d_in, const int* in_sizes, int n_in,
                              void* d_out, int out_size, void* d_ws, size_t ws_size,
                              hipStream_t stream) {
    const float* cxr = (const float*)d_in[0];
    const float* ehr = (const float*)d_in[1];
    const float* temp = (const float*)d_in[2];
    float* out = (float*)d_out;

    char* ws = (char*)d_ws;
    unsigned short* Ab = (unsigned short*)ws;                          // 8 MB
    unsigned short* Bb = (unsigned short*)(ws + 8u * 1024 * 1024);     // 8 MB
    float* inva = (float*)(ws + 16u * 1024 * 1024);
    float* invb = inva + N_ROWS;
    float* rs   = invb + N_ROWS;
    float* cs   = rs + N_ROWS;
    float* dg   = cs + N_ROWS;

    hipMemsetAsync(rs, 0, 2 * N_ROWS * sizeof(float), stream);
    norm_kernel<<<dim3((2 * N_ROWS) / 4), 256, 0, stream>>>(cxr, ehr, Ab, Bb, inva, invb);
    diag_kernel<<<dim3(N_ROWS / 4), 256, 0, stream>>>(cxr, ehr, inva, invb, temp, dg);
    gemm_lse_kernel<<<dim3(64, 64), 256, 0, stream>>>(Ab, Bb, temp, rs, cs);
    finalize_kernel<<<1, 256, 0, stream>>>(rs, cs, dg, temp, out);
}

// Round 2
// 127.316 us; speedup vs baseline: 1.0765x; 1.0765x over previous
//
#include <hip/hip_runtime.h>
#include <hip/hip_bf16.h>

#define N_ROWS 8192
#define D_DIM  512
#define NT     16   // K-tiles of BK=32

typedef __attribute__((ext_vector_type(8))) short short8;
typedef __attribute__((ext_vector_type(4))) float f32x4;

typedef const __attribute__((address_space(1))) void* gptr_t;
typedef __attribute__((address_space(3))) void* lptr_t;

static __device__ __forceinline__ void gload16(const void* g, void* l) {
    __builtin_amdgcn_global_load_lds((gptr_t)g, (lptr_t)l, 16, 0, 0);
}
#define VMCNT(n)  asm volatile("s_waitcnt vmcnt(" #n ")" ::: "memory")
#define BARRIER() __builtin_amdgcn_s_barrier()
#define SCHED0()  __builtin_amdgcn_sched_barrier(0)

// round-to-nearest-even f32 -> bf16 bits
static __device__ __forceinline__ unsigned short f2bf(float x) {
    unsigned u = __float_as_uint(x);
    unsigned r = (u + 0x7FFFu + ((u >> 16) & 1u)) >> 16;
    return (unsigned short)r;
}

// One wave per row: L2-normalize a row, write bf16, store 1/norm.
__global__ void norm_kernel(const float* __restrict__ cxr, const float* __restrict__ ehr,
                            unsigned short* __restrict__ cxr_b, unsigned short* __restrict__ ehr_b,
                            float* __restrict__ inva, float* __restrict__ invb) {
    const int row = blockIdx.x * 4 + (threadIdx.x >> 6);
    const int lane = threadIdx.x & 63;
    const float* src;
    unsigned short* dst;
    float* invp;
    int r;
    if (row < N_ROWS) {
        r = row; src = cxr + (size_t)r * D_DIM; dst = cxr_b + (size_t)r * D_DIM; invp = inva;
    } else {
        r = row - N_ROWS; src = ehr + (size_t)r * D_DIM; dst = ehr_b + (size_t)r * D_DIM; invp = invb;
    }
    const float4* s4 = (const float4*)(src + lane * 8);
    float4 a = s4[0], b = s4[1];
    float ss = a.x*a.x + a.y*a.y + a.z*a.z + a.w*a.w
             + b.x*b.x + b.y*b.y + b.z*b.z + b.w*b.w;
#pragma unroll
    for (int s = 1; s < 64; s <<= 1) ss += __shfl_xor(ss, s);
    float inv = 1.0f / sqrtf(fmaxf(ss, 1e-16f));
    if (lane == 0) invp[r] = inv;
    float va[8] = {a.x, a.y, a.z, a.w, b.x, b.y, b.z, b.w};
    short8 o;
#pragma unroll
    for (int j = 0; j < 8; ++j) o[j] = (short)f2bf(va[j] * inv);
    *(short8*)(dst + lane * 8) = o;
}

// One wave per row: diag_i = dot(cxr_i, ehr_i) * inva_i * invb_i / temp   (full fp32)
__global__ void diag_kernel(const float* __restrict__ cxr, const float* __restrict__ ehr,
                            const float* __restrict__ inva, const float* __restrict__ invb,
                            const float* __restrict__ temp, float* __restrict__ dg) {
    const int row = blockIdx.x * 4 + (threadIdx.x >> 6);
    const int lane = threadIdx.x & 63;
    const float4* a4 = (const float4*)(cxr + (size_t)row * D_DIM + lane * 8);
    const float4* b4 = (const float4*)(ehr + (size_t)row * D_DIM + lane * 8);
    float4 a0 = a4[0], a1 = a4[1];
    float4 b0 = b4[0], b1 = b4[1];
    float d = a0.x*b0.x + a0.y*b0.y + a0.z*b0.z + a0.w*b0.w
            + a1.x*b1.x + a1.y*b1.y + a1.z*b1.z + a1.w*b1.w;
#pragma unroll
    for (int s = 1; s < 64; s <<= 1) d += __shfl_xor(d, s);
    if (lane == 0) dg[row] = d * inva[row] * invb[row] / temp[0];
}

// 256x256 bf16 MFMA tile, BK=32, 8 waves (2x4), 4-deep LDS ring with counted vmcnt.
// Epilogue: exp((cos-1)/T), diag zeroed, row/col partial sums -> global atomics.
__global__ __launch_bounds__(512, 2) void gemm_lse_kernel(
        const unsigned short* __restrict__ A, const unsigned short* __restrict__ B,
        const float* __restrict__ temp,
        float* __restrict__ row_sum, float* __restrict__ col_sum) {
    __shared__ short As[4][8192];   // 4 x [256 rows][32 cols] bf16 = 64 KB
    __shared__ short Bs[4][8192];   // 64 KB
    __shared__ float rs_l[256];
    __shared__ float cs_l[256];

    const int tid = threadIdx.x;
    const int lane = tid & 63;
    const int wid = tid >> 6;
    const int bm = blockIdx.x, bn = blockIdx.y;
    const int wm = wid >> 2, wn = wid & 3;   // 2 x 4 wave grid; wave tile 128x64

    if (tid < 256) { rs_l[tid] = 0.f; cs_l[tid] = 0.f; }

    // staging: each K-tile = 256 rows x 32 cols; 2 gload lines of 128 rows per matrix
    const int srow = wid * 16 + (lane >> 2);     // row within a 128-row line
    const int scol = (lane & 3) * 8;             // element col within 32
    const unsigned short* gA = A + (size_t)(bm * 256 + srow) * D_DIM + scol;
    const unsigned short* gB = B + (size_t)(bn * 256 + srow) * D_DIM + scol;

#define STAGE_A(bf, t) do { \
    gload16(gA + (t) * 32,                &As[bf][wid * 512]); \
    gload16(gA + (t) * 32 + 128 * D_DIM,  &As[bf][4096 + wid * 512]); } while (0)
#define STAGE_B(bf, t) do { \
    gload16(gB + (t) * 32,                &Bs[bf][wid * 512]); \
    gload16(gB + (t) * 32 + 128 * D_DIM,  &Bs[bf][4096 + wid * 512]); } while (0)

    const int lr = lane & 15, g8 = (lane >> 4) * 8;
#define LDA(bf, m) (*(const short8*)&As[bf][(wm * 128 + (m) * 16 + lr) * 32 + g8])
#define LDB(bf, n) (*(const short8*)&Bs[bf][(wn * 64  + (n) * 16 + lr) * 32 + g8])

    // prologue: stage tiles 0..2 (12 loads); wait until tile 0 landed (8 still flying)
    STAGE_A(0, 0); STAGE_B(0, 0);
    STAGE_A(1, 1); STAGE_B(1, 1);
    STAGE_A(2, 2); STAGE_B(2, 2);

    f32x4 acc[8][4] = {};

    VMCNT(8);
    BARRIER();
    SCHED0();

    for (int t = 0; t < NT; ++t) {
        const int b = t & 3, nb = (t + 3) & 3;
        short8 bfr[4], afr[4];

        // ---- phase A: issue A-lines for tile t+3, compute m=0..3 ----
        if (t + 3 < NT) STAGE_A(nb, t + 3);
#pragma unroll
        for (int n = 0; n < 4; ++n) bfr[n] = LDB(b, n);
#pragma unroll
        for (int m = 0; m < 4; ++m) afr[m] = LDA(b, m);
        __builtin_amdgcn_s_setprio(1);
#pragma unroll
        for (int m = 0; m < 4; ++m)
#pragma unroll
            for (int n = 0; n < 4; ++n)
                acc[m][n] = __builtin_amdgcn_mfma_f32_16x16x32_bf16(afr[m], bfr[n], acc[m][n], 0, 0, 0);
        __builtin_amdgcn_s_setprio(0);

        // ---- phase B: issue B-lines for tile t+3, compute m=4..7 ----
        if (t + 3 < NT) STAGE_B(nb, t + 3);
#pragma unroll
        for (int m = 0; m < 4; ++m) afr[m] = LDA(b, m + 4);
        __builtin_amdgcn_s_setprio(1);
#pragma unroll
        for (int m = 0; m < 4; ++m)
#pragma unroll
            for (int n = 0; n < 4; ++n)
                acc[m + 4][n] = __builtin_amdgcn_mfma_f32_16x16x32_bf16(afr[m], bfr[n], acc[m + 4][n], 0, 0, 0);
        __builtin_amdgcn_s_setprio(0);

        // ---- end-of-tile sync: tile t+1 must be landed; keep rest in flight ----
        if (t < NT - 1) {
            if (t < NT - 3)       VMCNT(8);
            else if (t == NT - 3) VMCNT(4);
            else                  VMCNT(0);
            BARRIER();
            SCHED0();
        }
    }

    // ---- epilogue: exp + masked diag + row/col reduction ----
    const float invT = 1.0f / temp[0];
    const bool diagBlk = (bm == bn);

    float rowpart[32];
#pragma unroll
    for (int i = 0; i < 32; ++i) rowpart[i] = 0.f;
    float colpart[4] = {0.f, 0.f, 0.f, 0.f};

#pragma unroll
    for (int m = 0; m < 8; ++m)
#pragma unroll
        for (int n = 0; n < 4; ++n) {
            f32x4 a = acc[m][n];
#pragma unroll
            for (int r = 0; r < 4; ++r) {
                float e = __expf((a[r] - 1.0f) * invT);
                if (diagBlk) {
                    int grow = wm * 128 + m * 16 + (lane >> 4) * 4 + r;
                    int gcol = wn * 64 + n * 16 + (lane & 15);
                    if (grow == gcol) e = 0.f;
                }
                rowpart[m * 4 + r] += e;
                colpart[n] += e;
            }
        }

#pragma unroll
    for (int n = 0; n < 4; ++n) {
        float v = colpart[n];
        v += __shfl_xor(v, 16);
        v += __shfl_xor(v, 32);
        if (lane < 16) atomicAdd(&cs_l[wn * 64 + n * 16 + lane], v);
    }
#pragma unroll
    for (int idx = 0; idx < 32; ++idx) {
        float v = rowpart[idx];
        v += __shfl_xor(v, 1);
        v += __shfl_xor(v, 2);
        v += __shfl_xor(v, 4);
        v += __shfl_xor(v, 8);
        if ((lane & 15) == 0)
            atomicAdd(&rs_l[wm * 128 + (idx >> 2) * 16 + (lane >> 4) * 4 + (idx & 3)], v);
    }
    __syncthreads();
    if (tid < 256) atomicAdd(&row_sum[bm * 256 + tid], rs_l[tid]);
    else           atomicAdd(&col_sum[bn * 256 + (tid - 256)], cs_l[tid - 256]);
}

// loss = mean_i [ 2M + log(rs_i) + log(cs_i) - 2*diag_i ],  M = 1/temp
__global__ void finalize_kernel(const float* __restrict__ rs, const float* __restrict__ cs,
                                const float* __restrict__ dg, const float* __restrict__ temp,
                                float* __restrict__ out) {
    const float M = 1.0f / temp[0];
    float acc = 0.f;
    for (int i = threadIdx.x; i < N_ROWS; i += 256)
        acc += 2.f * M + __logf(rs[i]) + __logf(cs[i]) - 2.f * dg[i];
#pragma unroll
    for (int s = 1; s < 64; s <<= 1) acc += __shfl_xor(acc, s);
    __shared__ float wsum[4];
    if ((threadIdx.x & 63) == 0) wsum[threadIdx.x >> 6] = acc;
    __syncthreads();
    if (threadIdx.x == 0)
        out[0] = (wsum[0] + wsum[1] + wsum[2] + wsum[3]) / (float)N_ROWS;
}

extern "C" void kernel_launch(void* const* d_in, const int* in_sizes, int n_in,
                              void* d_out, int out_size, void* d_ws, size_t ws_size,
                              hipStream_t stream) {
    const float* cxr = (const float*)d_in[0];
    const float* ehr = (const float*)d_in[1];
    const float* temp = (const float*)d_in[2];
    float* out = (float*)d_out;

    char* ws = (char*)d_ws;
    unsigned short* Ab = (unsigned short*)ws;                          // 8 MB
    unsigned short* Bb = (unsigned short*)(ws + 8u * 1024 * 1024);     // 8 MB
    float* inva = (float*)(ws + 16u * 1024 * 1024);
    float* invb = inva + N_ROWS;
    float* rs   = invb + N_ROWS;
    float* cs   = rs + N_ROWS;
    float* dg   = cs + N_ROWS;

    hipMemsetAsync(rs, 0, 2 * N_ROWS * sizeof(float), stream);
    norm_kernel<<<dim3((2 * N_ROWS) / 4), 256, 0, stream>>>(cxr, ehr, Ab, Bb, inva, invb);
    diag_kernel<<<dim3(N_ROWS / 4), 256, 0, stream>>>(cxr, ehr, inva, invb, temp, dg);
    gemm_lse_kernel<<<dim3(32, 32), 512, 0, stream>>>(Ab, Bb, temp, rs, cs);
    finalize_kernel<<<1, 256, 0, stream>>>(rs, cs, dg, temp, out);
}

// Round 3
// 120.853 us; speedup vs baseline: 1.1340x; 1.0535x over previous
//
#include <hip/hip_runtime.h>
#include <hip/hip_bf16.h>

#define N_ROWS 8192
#define D_DIM  512
#define NT     16   // K-tiles of BK=32

typedef __attribute__((ext_vector_type(8))) short short8;
typedef __attribute__((ext_vector_type(4))) float f32x4;

typedef const __attribute__((address_space(1))) void* gptr_t;
typedef __attribute__((address_space(3))) void* lptr_t;

static __device__ __forceinline__ void gload16(const void* g, void* l) {
    __builtin_amdgcn_global_load_lds((gptr_t)g, (lptr_t)l, 16, 0, 0);
}
#define VMCNT(n)  asm volatile("s_waitcnt vmcnt(" #n ")" ::: "memory")
#define BARRIER() __builtin_amdgcn_s_barrier()
#define SCHED0()  __builtin_amdgcn_sched_barrier(0)

// round-to-nearest-even f32 -> bf16 bits
static __device__ __forceinline__ unsigned short f2bf(float x) {
    unsigned u = __float_as_uint(x);
    unsigned r = (u + 0x7FFFu + ((u >> 16) & 1u)) >> 16;
    return (unsigned short)r;
}

// One wave per row-index i: L2-normalize cxr_i and ehr_i, write bf16,
// and compute diag_i = dot(cxr_i, ehr_i)*inva*invb/temp (full fp32) in one pass.
__global__ void normdiag_kernel(const float* __restrict__ cxr, const float* __restrict__ ehr,
                                unsigned short* __restrict__ Ab, unsigned short* __restrict__ Bb,
                                const float* __restrict__ temp, float* __restrict__ dg) {
    const int row = blockIdx.x * 4 + (threadIdx.x >> 6);
    const int lane = threadIdx.x & 63;
    const float4* a4 = (const float4*)(cxr + (size_t)row * D_DIM + lane * 8);
    const float4* b4 = (const float4*)(ehr + (size_t)row * D_DIM + lane * 8);
    float4 a0 = a4[0], a1 = a4[1];
    float4 b0 = b4[0], b1 = b4[1];
    float sa = a0.x*a0.x + a0.y*a0.y + a0.z*a0.z + a0.w*a0.w
             + a1.x*a1.x + a1.y*a1.y + a1.z*a1.z + a1.w*a1.w;
    float sb = b0.x*b0.x + b0.y*b0.y + b0.z*b0.z + b0.w*b0.w
             + b1.x*b1.x + b1.y*b1.y + b1.z*b1.z + b1.w*b1.w;
    float dt = a0.x*b0.x + a0.y*b0.y + a0.z*b0.z + a0.w*b0.w
             + a1.x*b1.x + a1.y*b1.y + a1.z*b1.z + a1.w*b1.w;
#pragma unroll
    for (int s = 1; s < 64; s <<= 1) {
        sa += __shfl_xor(sa, s);
        sb += __shfl_xor(sb, s);
        dt += __shfl_xor(dt, s);
    }
    const float ia = 1.0f / sqrtf(fmaxf(sa, 1e-16f));
    const float ib = 1.0f / sqrtf(fmaxf(sb, 1e-16f));
    if (lane == 0) dg[row] = dt * ia * ib / temp[0];
    float va[8] = {a0.x, a0.y, a0.z, a0.w, a1.x, a1.y, a1.z, a1.w};
    float vb[8] = {b0.x, b0.y, b0.z, b0.w, b1.x, b1.y, b1.z, b1.w};
    short8 oa, ob;
#pragma unroll
    for (int j = 0; j < 8; ++j) {
        oa[j] = (short)f2bf(va[j] * ia);
        ob[j] = (short)f2bf(vb[j] * ib);
    }
    *(short8*)(Ab + (size_t)row * D_DIM + lane * 8) = oa;
    *(short8*)(Bb + (size_t)row * D_DIM + lane * 8) = ob;
}

// 256x256 bf16 MFMA tile, BK=32, 8 waves (2x4), 4-deep LDS ring, counted vmcnt.
// LDS slot-swizzle (T2): LDS[r][s'] holds global slot s'^((r>>1)&3); applied on
// the global SOURCE address (global_load_lds writes linearly) and on the read.
// Epilogue: exp((cos-1)/T), diag zeroed, row/col partial sums -> global atomics.
__global__ __launch_bounds__(512, 2) void gemm_lse_kernel(
        const unsigned short* __restrict__ A, const unsigned short* __restrict__ B,
        const float* __restrict__ temp,
        float* __restrict__ row_sum, float* __restrict__ col_sum) {
    __shared__ short As[4][8192];   // 4 x [256 rows][32 cols] bf16 = 64 KB
    __shared__ short Bs[4][8192];   // 64 KB
    __shared__ float rs_l[256];
    __shared__ float cs_l[256];

    const int tid = threadIdx.x;
    const int lane = tid & 63;
    const int wid = tid >> 6;
    const int bm = blockIdx.x, bn = blockIdx.y;
    const int wm = wid >> 2, wn = wid & 3;   // 2 x 4 wave grid; wave tile 128x64

    if (tid < 256) { rs_l[tid] = 0.f; cs_l[tid] = 0.f; }

    // staging: lane l writes LDS row (wid*16 + l>>2), slot (l&3); its global
    // source slot is (l&3)^((l>>3)&3)  [= (l&3)^((row>>1)&3), the T2 involution]
    const int srow = wid * 16 + (lane >> 2);
    const int scol = ((lane & 3) ^ ((lane >> 3) & 3)) * 8;
    const unsigned short* gA = A + (size_t)(bm * 256 + srow) * D_DIM + scol;
    const unsigned short* gB = B + (size_t)(bn * 256 + srow) * D_DIM + scol;

#define STAGE_A(bf, t) do { \
    gload16(gA + (t) * 32,                &As[bf][wid * 512]); \
    gload16(gA + (t) * 32 + 128 * D_DIM,  &As[bf][4096 + wid * 512]); } while (0)
#define STAGE_B(bf, t) do { \
    gload16(gB + (t) * 32,                &Bs[bf][wid * 512]); \
    gload16(gB + (t) * 32 + 128 * D_DIM,  &Bs[bf][4096 + wid * 512]); } while (0)

    // read: want global slot (lane>>4) of row (.. + lr); LDS slot = g ^ ((lr>>1)&3)
    const int lr = lane & 15;
    const int g8s = (((lane >> 4) ^ ((lane >> 1) & 3)) & 3) * 8;
#define LDA(bf, m) (*(const short8*)&As[bf][(wm * 128 + (m) * 16 + lr) * 32 + g8s])
#define LDB(bf, n) (*(const short8*)&Bs[bf][(wn * 64  + (n) * 16 + lr) * 32 + g8s])

    // prologue: stage tiles 0..2 (12 loads/wave); wait for tile 0 (8 still flying)
    STAGE_A(0, 0); STAGE_B(0, 0);
    STAGE_A(1, 1); STAGE_B(1, 1);
    STAGE_A(2, 2); STAGE_B(2, 2);

    f32x4 acc[8][4] = {};

    VMCNT(8);
    BARRIER();
    SCHED0();

    for (int t = 0; t < NT; ++t) {
        const int b = t & 3, nb = (t + 3) & 3;
        short8 bfr[4], afr[4];

        // ---- phase A: issue A-lines for tile t+3, compute m=0..3 ----
        if (t + 3 < NT) STAGE_A(nb, t + 3);
#pragma unroll
        for (int n = 0; n < 4; ++n) bfr[n] = LDB(b, n);
#pragma unroll
        for (int m = 0; m < 4; ++m) afr[m] = LDA(b, m);
        __builtin_amdgcn_s_setprio(1);
#pragma unroll
        for (int m = 0; m < 4; ++m)
#pragma unroll
            for (int n = 0; n < 4; ++n)
                acc[m][n] = __builtin_amdgcn_mfma_f32_16x16x32_bf16(afr[m], bfr[n], acc[m][n], 0, 0, 0);
        __builtin_amdgcn_s_setprio(0);

        // ---- phase B: issue B-lines for tile t+3, compute m=4..7 ----
        if (t + 3 < NT) STAGE_B(nb, t + 3);
#pragma unroll
        for (int m = 0; m < 4; ++m) afr[m] = LDA(b, m + 4);
        __builtin_amdgcn_s_setprio(1);
#pragma unroll
        for (int m = 0; m < 4; ++m)
#pragma unroll
            for (int n = 0; n < 4; ++n)
                acc[m + 4][n] = __builtin_amdgcn_mfma_f32_16x16x32_bf16(afr[m], bfr[n], acc[m + 4][n], 0, 0, 0);
        __builtin_amdgcn_s_setprio(0);

        // ---- end-of-tile sync: tile t+1 landed; rest stays in flight ----
        // per-wave: 4 loads/tile; outstanding tiles {t+1..min(t+3,NT-1)}
        if (t < NT - 1) {
            if (t < NT - 3)       VMCNT(8);
            else if (t == NT - 3) VMCNT(4);
            else                  VMCNT(0);
            BARRIER();
            SCHED0();
        }
    }

    // ---- epilogue: exp + masked diag + row/col reduction ----
    const float invT = 1.0f / temp[0];
    const bool diagBlk = (bm == bn);

    float rowpart[32];
#pragma unroll
    for (int i = 0; i < 32; ++i) rowpart[i] = 0.f;
    float colpart[4] = {0.f, 0.f, 0.f, 0.f};

#pragma unroll
    for (int m = 0; m < 8; ++m)
#pragma unroll
        for (int n = 0; n < 4; ++n) {
            f32x4 a = acc[m][n];
#pragma unroll
            for (int r = 0; r < 4; ++r) {
                float e = __expf((a[r] - 1.0f) * invT);
                if (diagBlk) {
                    int grow = wm * 128 + m * 16 + (lane >> 4) * 4 + r;
                    int gcol = wn * 64 + n * 16 + (lane & 15);
                    if (grow == gcol) e = 0.f;
                }
                rowpart[m * 4 + r] += e;
                colpart[n] += e;
            }
        }

#pragma unroll
    for (int n = 0; n < 4; ++n) {
        float v = colpart[n];
        v += __shfl_xor(v, 16);
        v += __shfl_xor(v, 32);
        if (lane < 16) atomicAdd(&cs_l[wn * 64 + n * 16 + lane], v);
    }
#pragma unroll
    for (int idx = 0; idx < 32; ++idx) {
        float v = rowpart[idx];
        v += __shfl_xor(v, 1);
        v += __shfl_xor(v, 2);
        v += __shfl_xor(v, 4);
        v += __shfl_xor(v, 8);
        if ((lane & 15) == 0)
            atomicAdd(&rs_l[wm * 128 + (idx >> 2) * 16 + (lane >> 4) * 4 + (idx & 3)], v);
    }
    __syncthreads();
    if (tid < 256) atomicAdd(&row_sum[bm * 256 + tid], rs_l[tid]);
    else           atomicAdd(&col_sum[bn * 256 + (tid - 256)], cs_l[tid - 256]);
}

// loss = mean_i [ 2M + log(rs_i) + log(cs_i) - 2*diag_i ],  M = 1/temp
__global__ void finalize_kernel(const float* __restrict__ rs, const float* __restrict__ cs,
                                const float* __restrict__ dg, const float* __restrict__ temp,
                                float* __restrict__ out) {
    const float M = 1.0f / temp[0];
    float acc = 0.f;
    for (int i = threadIdx.x; i < N_ROWS; i += 256)
        acc += 2.f * M + __logf(rs[i]) + __logf(cs[i]) - 2.f * dg[i];
#pragma unroll
    for (int s = 1; s < 64; s <<= 1) acc += __shfl_xor(acc, s);
    __shared__ float wsum[4];
    if ((threadIdx.x & 63) == 0) wsum[threadIdx.x >> 6] = acc;
    __syncthreads();
    if (threadIdx.x == 0)
        out[0] = (wsum[0] + wsum[1] + wsum[2] + wsum[3]) / (float)N_ROWS;
}

extern "C" void kernel_launch(void* const* d_in, const int* in_sizes, int n_in,
                              void* d_out, int out_size, void* d_ws, size_t ws_size,
                              hipStream_t stream) {
    const float* cxr = (const float*)d_in[0];
    const float* ehr = (const float*)d_in[1];
    const float* temp = (const float*)d_in[2];
    float* out = (float*)d_out;

    char* ws = (char*)d_ws;
    unsigned short* Ab = (unsigned short*)ws;                          // 8 MB
    unsigned short* Bb = (unsigned short*)(ws + 8u * 1024 * 1024);     // 8 MB
    float* rs = (float*)(ws + 16u * 1024 * 1024);
    float* cs = rs + N_ROWS;
    float* dg = cs + N_ROWS;

    hipMemsetAsync(rs, 0, 2 * N_ROWS * sizeof(float), stream);
    normdiag_kernel<<<dim3(N_ROWS / 4), 256, 0, stream>>>(cxr, ehr, Ab, Bb, temp, dg);
    gemm_lse_kernel<<<dim3(32, 32), 512, 0, stream>>>(Ab, Bb, temp, rs, cs);
    finalize_kernel<<<1, 256, 0, stream>>>(rs, cs, dg, temp, out);
}